// Round 1
// baseline (195.873 us; speedup 1.0000x reference)
//
#include <hip/hip_runtime.h>
#include <math.h>

// Problem constants (fixed by setup_inputs)
#define NX 192
#define NY 192
#define NPIX (NX * NY)     // 36864
#define ETLN 16
#define DATOMS 4000
#define PPT 4              // pixels per thread (amortizes db fetch)
#define TPB 256
#define PXB (NPIX / (TPB * PPT))  // 36 pixel-blocks, exact

typedef float v2f __attribute__((ext_vector_type(2)));

// ---- ws layout ----
// rec   : DATOMS*16 floats = 256000 B  (normalized db rows; d2 folded into first masked-out col)
// d2arr : DATOMS floats    =  16000 B  (fallback if no masked-out column exists)
// s2arr : NPIX floats      = 147456 B
// pf    : S*NPIX floats    (partial best scores per atom-chunk)
// pi    : S*NPIX ints      (partial best indices)
#define OFF_REC   0
#define OFF_D2    256000
#define OFF_S2    272000
#define OFF_PART  419456

__device__ __forceinline__ int mask_and_z(const float* __restrict__ delta_ms,
                                          float* mask) {
    int z = -1;
#pragma unroll
    for (int e = 0; e < ETLN; ++e) {
        float m = (delta_ms[e] * 1e-3f < 1e-3f) ? 1.0f : 0.0f;
        mask[e] = m;
        if (m == 0.0f && z < 0) z = e;
    }
    return z;
}

__global__ __launch_bounds__(256) void prep_db(
        const float* __restrict__ db_mag, const float* __restrict__ delta_ms,
        float* __restrict__ rec, float* __restrict__ d2arr) {
    int j = blockIdx.x * blockDim.x + threadIdx.x;
    if (j >= DATOMS) return;
    float mask[ETLN];
    int z = mask_and_z(delta_ms, mask);

    float v[ETLN];
    float ss = 0.f;
#pragma unroll
    for (int e = 0; e < ETLN; ++e) {
        float x = db_mag[j * ETLN + e] * mask[e];
        v[e] = x;
        ss += x * x;
    }
    float n = sqrtf(ss);
    float d2 = 0.f;
#pragma unroll
    for (int e = 0; e < ETLN; ++e) {
        float y = (n > 0.f) ? (v[e] / n) : 0.f;
        if (!isfinite(y)) y = 0.f;      // nan_to_num semantics
        v[e] = y;
        d2 += y * y;
    }
    d2arr[j] = d2;
    if (z >= 0) v[z] = d2;              // sentinel column carries d2
#pragma unroll
    for (int e = 0; e < ETLN; ++e) rec[j * ETLN + e] = v[e];
}

__global__ __launch_bounds__(TPB) void match_chunk(
        const float* __restrict__ sig, const float* __restrict__ delta_ms,
        const float* __restrict__ rec, const float* __restrict__ d2arr,
        float* __restrict__ pf, int* __restrict__ pi,
        float* __restrict__ s2arr, int nchunks) {
    const int pb = blockIdx.x;
    const int sc = blockIdx.y;
    const int chunk = (DATOMS + nchunks - 1) / nchunks;
    const int j0 = sc * chunk;
    const int j1 = min(DATOMS, j0 + chunk);

    float mask[ETLN];
    int z = mask_and_z(delta_ms, mask);

    const int pbase = pb * (TPB * PPT) + threadIdx.x;

    // Per-pixel preprocessing: t[e] = -2 * s[e]  (with sentinel t[z] = 1)
    v2f tp[PPT][ETLN / 2];
    float s2v[PPT];
#pragma unroll
    for (int r = 0; r < PPT; ++r) {
        int p = pbase + r * TPB;
        const float4* sp = (const float4*)(sig + (size_t)p * ETLN);
        float x[ETLN];
        float4 a0 = sp[0], a1 = sp[1], a2 = sp[2], a3 = sp[3];
        x[0]=a0.x; x[1]=a0.y; x[2]=a0.z; x[3]=a0.w;
        x[4]=a1.x; x[5]=a1.y; x[6]=a1.z; x[7]=a1.w;
        x[8]=a2.x; x[9]=a2.y; x[10]=a2.z; x[11]=a2.w;
        x[12]=a3.x; x[13]=a3.y; x[14]=a3.z; x[15]=a3.w;

        // first normalize over all 16
        float n1s = 0.f;
#pragma unroll
        for (int e = 0; e < ETLN; ++e) n1s += x[e] * x[e];
        float n1 = sqrtf(n1s);
#pragma unroll
        for (int e = 0; e < ETLN; ++e) {
            float y = (n1 > 0.f) ? (x[e] / n1) : 0.f;
            if (!isfinite(y)) y = 0.f;
            x[e] = y * mask[e];         // apply SE mask
        }
        // second normalize over masked columns
        float n2s = 0.f;
#pragma unroll
        for (int e = 0; e < ETLN; ++e) n2s += x[e] * x[e];
        float n2 = sqrtf(n2s);
        float s2 = 0.f;
        float t[ETLN];
#pragma unroll
        for (int e = 0; e < ETLN; ++e) {
            float y = (n2 > 0.f) ? (x[e] / n2) : 0.f;
            if (!isfinite(y)) y = 0.f;
            s2 += y * y;
            t[e] = -2.0f * y;
        }
        if (z >= 0) t[z] = 1.0f;        // picks up d2 from sentinel column
        s2v[r] = s2;
        if (sc == 0) s2arr[p] = s2;
#pragma unroll
        for (int k = 0; k < ETLN / 2; ++k) {
            v2f q; q.x = t[2 * k]; q.y = t[2 * k + 1];
            tp[r][k] = q;
        }
    }
    (void)s2v;

    float bestf[PPT];
    int bestj[PPT];
#pragma unroll
    for (int r = 0; r < PPT; ++r) { bestf[r] = 3.0e38f; bestj[r] = 0; }

    const float4* rec4 = (const float4*)rec;
    for (int j = j0; j < j1; ++j) {
        // wave-uniform address: all lanes hit the same L1 line (8 KB chunk resident)
        float4 A = rec4[4 * j + 0];
        float4 B = rec4[4 * j + 1];
        float4 C = rec4[4 * j + 2];
        float4 Dq = rec4[4 * j + 3];
        v2f q[8];
        q[0].x=A.x;  q[0].y=A.y;  q[1].x=A.z;  q[1].y=A.w;
        q[2].x=B.x;  q[2].y=B.y;  q[3].x=B.z;  q[3].y=B.w;
        q[4].x=C.x;  q[4].y=C.y;  q[5].x=C.z;  q[5].y=C.w;
        q[6].x=Dq.x; q[6].y=Dq.y; q[7].x=Dq.z; q[7].y=Dq.w;
        float base = (z < 0) ? d2arr[j] : 0.0f;   // uniform branch; z=1 here
#pragma unroll
        for (int r = 0; r < PPT; ++r) {
            v2f acc; acc.x = 0.f; acc.y = 0.f;
#pragma unroll
            for (int k = 0; k < 8; ++k)
                acc = __builtin_elementwise_fma(q[k], tp[r][k], acc);
            float f = acc.x + acc.y + base;       // f_j = d2 - 2*dot
            if (f < bestf[r]) { bestf[r] = f; bestj[r] = j; }  // strict <: first min
        }
    }

#pragma unroll
    for (int r = 0; r < PPT; ++r) {
        int p = pbase + r * TPB;
        pf[(size_t)sc * NPIX + p] = bestf[r];
        pi[(size_t)sc * NPIX + p] = bestj[r];
    }
}

__global__ __launch_bounds__(256) void merge_out(
        const float* __restrict__ pf, const int* __restrict__ pi,
        const float* __restrict__ s2arr, const float* __restrict__ t2s,
        const float* __restrict__ b1s, float* __restrict__ out, int nchunks) {
    int p = blockIdx.x * blockDim.x + threadIdx.x;
    if (p >= NPIX) return;
    float bf = 3.0e38f;
    int bj = 0;
    for (int sc = 0; sc < nchunks; ++sc) {
        float f = pf[(size_t)sc * NPIX + p];
        int j = pi[(size_t)sc * NPIX + p];
        if (f < bf) { bf = f; bj = j; }   // ascending sc => first-min semantics
    }
    out[p] = t2s[bj];
    out[NPIX + p] = b1s[bj];
    out[2 * NPIX + p] = sqrtf(fmaxf(bf + s2arr[p], 0.0f));
}

extern "C" void kernel_launch(void* const* d_in, const int* in_sizes, int n_in,
                              void* d_out, int out_size, void* d_ws, size_t ws_size,
                              hipStream_t stream) {
    const float* sig    = (const float*)d_in[0];  // [192,192,16]
    const float* db_mag = (const float*)d_in[1];  // [4000,16]
    const float* t2s    = (const float*)d_in[2];  // [4000]
    const float* b1s    = (const float*)d_in[3];  // [4000]
    const float* delta  = (const float*)d_in[4];  // [16]

    char* ws = (char*)d_ws;
    float* rec   = (float*)(ws + OFF_REC);
    float* d2arr = (float*)(ws + OFF_D2);
    float* s2arr = (float*)(ws + OFF_S2);

    int S = 32;
    while (S > 1 && (size_t)OFF_PART + (size_t)S * NPIX * 8 > ws_size) S >>= 1;
    float* pf = (float*)(ws + OFF_PART);
    int*   pi = (int*)(ws + OFF_PART + (size_t)S * NPIX * 4);

    prep_db<<<(DATOMS + 255) / 256, 256, 0, stream>>>(db_mag, delta, rec, d2arr);
    dim3 grid(PXB, S);
    match_chunk<<<grid, TPB, 0, stream>>>(sig, delta, rec, d2arr, pf, pi, s2arr, S);
    merge_out<<<(NPIX + 255) / 256, 256, 0, stream>>>(pf, pi, s2arr, t2s, b1s,
                                                      (float*)d_out, S);
}

// Round 3
// 170.213 us; speedup vs baseline: 1.1508x; 1.1508x over previous
//
#include <hip/hip_runtime.h>
#include <hip/hip_bf16.h>
#include <math.h>

// Problem constants (fixed by setup_inputs)
#define NX 192
#define NY 192
#define NPIX (NX * NY)     // 36864
#define ETLN 16
#define DATOMS 4000
#define TILES_TOTAL 250    // 4000 / 16
#define PXBLK (NPIX / 256) // 144 pixel blocks (256 px per block, 64 per wave)

typedef __attribute__((ext_vector_type(8))) short short8;
typedef __attribute__((ext_vector_type(4))) float f32x4;
typedef unsigned short ushort;

// ---- ws layout (bytes) ----
// A1  : 4000 * 32 ushort = 256000   rows [Ah(16)|Am(16)]
// A2  : 4000 * 32 ushort = 256000   rows [Ah(16)|Al(16)]
// REC : 4000 * 16 f32    = 256000   exact f32 atoms (sentinel col = d2)
// CAND: SCH * NPIX int2             per-chunk top-2 candidate indices
#define OFF_A1   0
#define OFF_A2   256000
#define OFF_REC  512000
#define OFF_CAND 768000

__device__ __forceinline__ int mask_and_z(const float* __restrict__ delta_ms,
                                          float* mask) {
    int z = -1;
#pragma unroll
    for (int e = 0; e < ETLN; ++e) {
        float m = (delta_ms[e] * 1e-3f < 1e-3f) ? 1.0f : 0.0f;
        mask[e] = m;
        if (m == 0.0f && z < 0) z = e;
    }
    return z;
}

// bf16 split: returns bf16 bits of x (RN); *rem = x - float(bf16(x)) (exact in f32)
__device__ __forceinline__ ushort bfsplit(float x, float* rem) {
    __hip_bfloat16 h = __float2bfloat16(x);
    *rem = x - __bfloat162float(h);
    union { __hip_bfloat16 h; ushort u; } cv;
    cv.h = h;
    return cv.u;
}

// Two-stage normalize of one signal row -> t = -2*s (t[z]=1 sentinel), s2 = ||s||^2
__device__ __forceinline__ void compute_t(const float* __restrict__ row,
                                          const float* mask, int z,
                                          float* tv, float* s2out) {
    float x[ETLN];
    const float4* r4 = (const float4*)row;
#pragma unroll
    for (int q = 0; q < 4; ++q) {
        float4 a = r4[q];
        x[4 * q + 0] = a.x; x[4 * q + 1] = a.y;
        x[4 * q + 2] = a.z; x[4 * q + 3] = a.w;
    }
    float n1s = 0.f;
#pragma unroll
    for (int e = 0; e < ETLN; ++e) n1s += x[e] * x[e];
    float n1 = sqrtf(n1s);
#pragma unroll
    for (int e = 0; e < ETLN; ++e) {
        float y = (n1 > 0.f) ? (x[e] / n1) : 0.f;
        if (!isfinite(y)) y = 0.f;
        x[e] = y * mask[e];
    }
    float n2s = 0.f;
#pragma unroll
    for (int e = 0; e < ETLN; ++e) n2s += x[e] * x[e];
    float n2 = sqrtf(n2s);
    float s2 = 0.f;
#pragma unroll
    for (int e = 0; e < ETLN; ++e) {
        float y = (n2 > 0.f) ? (x[e] / n2) : 0.f;
        if (!isfinite(y)) y = 0.f;
        s2 += y * y;
        tv[e] = -2.0f * y;
    }
    if (z >= 0) tv[z] = 1.0f;
    *s2out = s2;
}

// prep: atoms -> normalized f32 rows (sentinel col = d2) + bf16 split rows
__global__ __launch_bounds__(256) void prep(
        const float* __restrict__ db_mag, const float* __restrict__ delta_ms,
        ushort* __restrict__ A1, ushort* __restrict__ A2,
        float* __restrict__ recf) {
    int t = blockIdx.x * 256 + threadIdx.x;
    if (t >= DATOMS) return;
    float mask[ETLN];
    int z = mask_and_z(delta_ms, mask);

    float v[ETLN];
    float ss = 0.f;
#pragma unroll
    for (int e = 0; e < ETLN; ++e) {
        float x = db_mag[t * ETLN + e] * mask[e];
        v[e] = x;
        ss += x * x;
    }
    float n = sqrtf(ss);
    float d2 = 0.f;
#pragma unroll
    for (int e = 0; e < ETLN; ++e) {
        float y = (n > 0.f) ? (v[e] / n) : 0.f;
        if (!isfinite(y)) y = 0.f;
        v[e] = y;
        d2 += y * y;
    }
    if (z >= 0) v[z] = d2;   // sentinel column carries d2 (t[z]=1 picks it up)
#pragma unroll
    for (int e = 0; e < ETLN; ++e) {
        recf[t * ETLN + e] = v[e];
        float r1, r2, dmy;
        ushort hb = bfsplit(v[e], &r1);
        ushort mb = bfsplit(r1, &r2);
        ushort lb = bfsplit(r2, &dmy);
        A1[t * 32 + e]      = hb;  A1[t * 32 + 16 + e] = mb;
        A2[t * 32 + e]      = hb;  A2[t * 32 + 16 + e] = lb;
    }
}

// match: 64 pixels/wave x one atom chunk; split-bf16 MFMA scores, per-chunk top-2
__global__ __launch_bounds__(256) void match(
        const ushort* __restrict__ A1, const ushort* __restrict__ A2,
        const float* __restrict__ sig, const float* __restrict__ delta_ms,
        int2* __restrict__ cand, int CT) {
    const int lane = threadIdx.x & 63;
    const int wv   = threadIdx.x >> 6;
    const int quad = lane >> 4;
    const int l15  = lane & 15;
    const bool lo  = (quad < 2);
    const bool hi8 = (quad & 1) != 0;

    float mask[ETLN];
    int z = mask_and_z(delta_ms, mask);

    // Build B fragments on the fly: V1=[th|tm], V2=[tm|th], V3=[tl|th] along K=32
    int pix[4];
    short8 V1[4], V2[4], V3[4];
#pragma unroll
    for (int g = 0; g < 4; ++g) {
        int p = blockIdx.x * 256 + wv * 64 + g * 16 + l15;
        pix[g] = p;
        float tv[ETLN], s2;
        compute_t(sig + (size_t)p * ETLN, mask, z, tv, &s2);
        ushort hs[ETLN], ms[ETLN], ls[ETLN];
#pragma unroll
        for (int e = 0; e < ETLN; ++e) {
            float r1, r2, dmy;
            hs[e] = bfsplit(tv[e], &r1);
            ms[e] = bfsplit(r1, &r2);
            ls[e] = bfsplit(r2, &dmy);
        }
#pragma unroll
        for (int i = 0; i < 8; ++i) {
            ushort hv = hi8 ? hs[i + 8] : hs[i];
            ushort mv = hi8 ? ms[i + 8] : ms[i];
            ushort lv = hi8 ? ls[i + 8] : ls[i];
            V1[g][i] = (short)(lo ? hv : mv);
            V2[g][i] = (short)(lo ? mv : hv);
            V3[g][i] = (short)(lo ? lv : hv);
        }
    }

    float b1f[4], b2f[4];
    int b1j[4], b2j[4];
#pragma unroll
    for (int g = 0; g < 4; ++g) {
        b1f[g] = 3.0e38f; b2f[g] = 3.0e38f; b1j[g] = 0; b2j[g] = 0;
    }

    const int jbase = blockIdx.y * CT * 16;
    const short8* a1p = (const short8*)A1;
    const short8* a2p = (const short8*)A2;
    // lane's A-frag for tile t: atom row m=l15, k-span quad*8
    int idx0 = (jbase + l15) * 4 + quad;
    short8 a1 = a1p[idx0];
    short8 a2 = a2p[idx0];

    for (int t = 0; t < CT; ++t) {
        int tn = (t + 1 < CT) ? (t + 1) : t;
        int idxn = (jbase + tn * 16 + l15) * 4 + quad;
        short8 na1 = a1p[idxn];
        short8 na2 = a2p[idxn];

        f32x4 acc[4];
#pragma unroll
        for (int g = 0; g < 4; ++g) acc[g] = (f32x4){0.f, 0.f, 0.f, 0.f};
#pragma unroll
        for (int g = 0; g < 4; ++g)
            acc[g] = __builtin_amdgcn_mfma_f32_16x16x32_bf16(a1, V1[g], acc[g], 0, 0, 0);
#pragma unroll
        for (int g = 0; g < 4; ++g)
            acc[g] = __builtin_amdgcn_mfma_f32_16x16x32_bf16(a1, V2[g], acc[g], 0, 0, 0);
#pragma unroll
        for (int g = 0; g < 4; ++g)
            acc[g] = __builtin_amdgcn_mfma_f32_16x16x32_bf16(a2, V3[g], acc[g], 0, 0, 0);

        const int j0 = jbase + t * 16 + quad * 4;  // C row = quad*4 + r
#pragma unroll
        for (int g = 0; g < 4; ++g) {
#pragma unroll
            for (int r = 0; r < 4; ++r) {
                float f = acc[g][r];
                int j = j0 + r;
                bool c1 = f < b1f[g];
                bool c2 = f < b2f[g];
                b2f[g] = c1 ? b1f[g] : (c2 ? f : b2f[g]);
                b2j[g] = c1 ? b1j[g] : (c2 ? j : b2j[g]);
                b1f[g] = c1 ? f : b1f[g];
                b1j[g] = c1 ? j : b1j[g];
            }
        }
        a1 = na1;
        a2 = na2;
    }

    // Exact cross-quad merge of sorted top-2 pairs (disjoint atom sets per quad)
#pragma unroll
    for (int g = 0; g < 4; ++g) {
        float p1 = b1f[g], p2 = b2f[g];
        int i1 = b1j[g], i2 = b2j[g];
#pragma unroll
        for (int off = 16; off <= 32; off <<= 1) {
            float q1 = __shfl_xor(p1, off);
            int   k1 = __shfl_xor(i1, off);
            float q2 = __shfl_xor(p2, off);
            int   k2 = __shfl_xor(i2, off);
            bool w = (q1 < p1) || (q1 == p1 && k1 < i1);
            float t1 = w ? q1 : p1;  int ti1 = w ? k1 : i1;
            float m  = w ? p1 : q1;  int mi  = w ? i1 : k1;  // loser's first
            float s  = w ? q2 : p2;  int si  = w ? k2 : i2;  // winner's second
            bool w2 = (s < m) || (s == m && si < mi);
            p1 = t1; i1 = ti1;
            p2 = w2 ? s : m;
            i2 = w2 ? si : mi;
        }
        if (lane < 16)
            cand[(size_t)blockIdx.y * NPIX + pix[g]] = make_int2(i1, i2);
    }
}

// merge: exact f32 rescore of 2*SCH candidates per pixel, first-min tie-break
__global__ __launch_bounds__(256) void merge(
        const float* __restrict__ sig, const float* __restrict__ recf,
        const float* __restrict__ t2s, const float* __restrict__ b1s,
        const float* __restrict__ delta_ms, const int2* __restrict__ cand,
        float* __restrict__ out, int SCH) {
    int p = blockIdx.x * 256 + threadIdx.x;
    if (p >= NPIX) return;
    float mask[ETLN];
    int z = mask_and_z(delta_ms, mask);
    float tv[ETLN], s2;
    compute_t(sig + (size_t)p * ETLN, mask, z, tv, &s2);

    float bf = 3.0e38f;
    int bj = 0x7FFFFFFF;
    for (int c = 0; c < SCH; ++c) {
        int2 jj = cand[(size_t)c * NPIX + p];
#pragma unroll
        for (int h = 0; h < 2; ++h) {
            int j = (h == 0) ? jj.x : jj.y;
            const float* rr = recf + (size_t)j * ETLN;
            float f = 0.f;
#pragma unroll
            for (int e = 0; e < ETLN; ++e) f = fmaf(rr[e], tv[e], f);  // d2 - 2*dot
            if (f < bf || (f == bf && j < bj)) { bf = f; bj = j; }
        }
    }
    out[p] = t2s[bj];
    out[NPIX + p] = b1s[bj];
    out[2 * NPIX + p] = sqrtf(fmaxf(bf + s2, 0.0f));
}

extern "C" void kernel_launch(void* const* d_in, const int* in_sizes, int n_in,
                              void* d_out, int out_size, void* d_ws, size_t ws_size,
                              hipStream_t stream) {
    const float* sig    = (const float*)d_in[0];  // [192,192,16]
    const float* db_mag = (const float*)d_in[1];  // [4000,16]
    const float* t2s    = (const float*)d_in[2];  // [4000]
    const float* b1s    = (const float*)d_in[3];  // [4000]
    const float* delta  = (const float*)d_in[4];  // [16]

    char* ws = (char*)d_ws;
    ushort* A1   = (ushort*)(ws + OFF_A1);
    ushort* A2   = (ushort*)(ws + OFF_A2);
    float*  recf = (float*)(ws + OFF_REC);
    int2*   cand = (int2*)(ws + OFF_CAND);

    // SCH must divide 250 tiles evenly: 5 -> 2 -> 1 (ws fallback)
    int SCH = 5;
    if ((size_t)OFF_CAND + (size_t)SCH * NPIX * sizeof(int2) > ws_size) SCH = 2;
    if ((size_t)OFF_CAND + (size_t)SCH * NPIX * sizeof(int2) > ws_size) SCH = 1;
    int CT = TILES_TOTAL / SCH;

    prep<<<(DATOMS + 255) / 256, 256, 0, stream>>>(db_mag, delta, A1, A2, recf);
    dim3 grid(PXBLK, SCH);
    match<<<grid, 256, 0, stream>>>(A1, A2, sig, delta, cand, CT);
    merge<<<PXBLK, 256, 0, stream>>>(sig, recf, t2s, b1s, delta, cand,
                                     (float*)d_out, SCH);
}

// Round 4
// 149.242 us; speedup vs baseline: 1.3124x; 1.1405x over previous
//
#include <hip/hip_runtime.h>
#include <hip/hip_bf16.h>
#include <math.h>

// Problem constants (fixed by setup_inputs)
#define NX 192
#define NY 192
#define NPIX (NX * NY)     // 36864
#define ETLN 16
#define DATOMS 4000
#define TILES_TOTAL 250    // 4000 / 16
#define PXB (NPIX / 128)   // 288 pixel blocks (128 px per block, 32 per wave)

typedef __attribute__((ext_vector_type(8))) short short8;
typedef __attribute__((ext_vector_type(4))) float f32x4;
typedef unsigned short ushort;
typedef unsigned int uint;

// ---- ws layout (bytes) ----
// A1  : 4000 * 32 ushort = 256000   rows [Ah(16)|Am(16)]
// A2  : 4000 * 32 ushort = 256000   rows [Ah(16)|Al(16)]
// REC : 4000 * 16 f32    = 256000   exact f32 atoms (sentinel col = d2)
// CAND: SCH * NPIX int2             per-chunk top-2 candidate indices
#define OFF_A1   0
#define OFF_A2   256000
#define OFF_REC  512000
#define OFF_CAND 768000

__device__ __forceinline__ int mask_and_z(const float* __restrict__ delta_ms,
                                          float* mask) {
    int z = -1;
#pragma unroll
    for (int e = 0; e < ETLN; ++e) {
        float m = (delta_ms[e] * 1e-3f < 1e-3f) ? 1.0f : 0.0f;
        mask[e] = m;
        if (m == 0.0f && z < 0) z = e;
    }
    return z;
}

// bf16 split: returns bf16 bits of x (RN); *rem = x - float(bf16(x)) (exact in f32)
__device__ __forceinline__ ushort bfsplit(float x, float* rem) {
    __hip_bfloat16 h = __float2bfloat16(x);
    *rem = x - __bfloat162float(h);
    union { __hip_bfloat16 h; ushort u; } cv;
    cv.h = h;
    return cv.u;
}

// Two-stage normalize of one signal row -> t = -2*s (t[z]=1 sentinel), s2 = ||s||^2
__device__ __forceinline__ void compute_t(const float* __restrict__ row,
                                          const float* mask, int z,
                                          float* tv, float* s2out) {
    float x[ETLN];
    const float4* r4 = (const float4*)row;
#pragma unroll
    for (int q = 0; q < 4; ++q) {
        float4 a = r4[q];
        x[4 * q + 0] = a.x; x[4 * q + 1] = a.y;
        x[4 * q + 2] = a.z; x[4 * q + 3] = a.w;
    }
    float n1s = 0.f;
#pragma unroll
    for (int e = 0; e < ETLN; ++e) n1s += x[e] * x[e];
    float n1 = sqrtf(n1s);
#pragma unroll
    for (int e = 0; e < ETLN; ++e) {
        float y = (n1 > 0.f) ? (x[e] / n1) : 0.f;
        if (!isfinite(y)) y = 0.f;
        x[e] = y * mask[e];
    }
    float n2s = 0.f;
#pragma unroll
    for (int e = 0; e < ETLN; ++e) n2s += x[e] * x[e];
    float n2 = sqrtf(n2s);
    float s2 = 0.f;
#pragma unroll
    for (int e = 0; e < ETLN; ++e) {
        float y = (n2 > 0.f) ? (x[e] / n2) : 0.f;
        if (!isfinite(y)) y = 0.f;
        s2 += y * y;
        tv[e] = -2.0f * y;
    }
    if (z >= 0) tv[z] = 1.0f;
    *s2out = s2;
}

// prep: atoms -> normalized f32 rows (sentinel col = d2) + bf16 split rows
__global__ __launch_bounds__(256) void prep(
        const float* __restrict__ db_mag, const float* __restrict__ delta_ms,
        ushort* __restrict__ A1, ushort* __restrict__ A2,
        float* __restrict__ recf) {
    int t = blockIdx.x * 256 + threadIdx.x;
    if (t >= DATOMS) return;
    float mask[ETLN];
    int z = mask_and_z(delta_ms, mask);

    float v[ETLN];
    float ss = 0.f;
#pragma unroll
    for (int e = 0; e < ETLN; ++e) {
        float x = db_mag[t * ETLN + e] * mask[e];
        v[e] = x;
        ss += x * x;
    }
    float n = sqrtf(ss);
    float d2 = 0.f;
#pragma unroll
    for (int e = 0; e < ETLN; ++e) {
        float y = (n > 0.f) ? (v[e] / n) : 0.f;
        if (!isfinite(y)) y = 0.f;
        v[e] = y;
        d2 += y * y;
    }
    if (z >= 0) v[z] = d2;   // sentinel column carries d2 (t[z]=1 picks it up)
#pragma unroll
    for (int e = 0; e < ETLN; ++e) {
        recf[t * ETLN + e] = v[e];
        float r1, r2, dmy;
        ushort hb = bfsplit(v[e], &r1);
        ushort mb = bfsplit(r1, &r2);
        ushort lb = bfsplit(r2, &dmy);
        A1[t * 32 + e]      = hb;  A1[t * 32 + 16 + e] = mb;
        A2[t * 32 + e]      = hb;  A2[t * 32 + 16 + e] = lb;
    }
}

// match: 32 pixels/wave x one atom chunk; split-bf16 MFMA, packed-key top-2.
// Score f = 3 + d2 - 2*dot lives in (2,4) -> one IEEE exponent -> mantissa
// bits are order-preserving; key = (bits(f)<<9 & 0xFFFFF000) | atom_index.
__global__ __launch_bounds__(256, 4) void match(
        const ushort* __restrict__ A1, const ushort* __restrict__ A2,
        const float* __restrict__ sig, const float* __restrict__ delta_ms,
        int2* __restrict__ cand, int CT) {
    const int lane = threadIdx.x & 63;
    const int wv   = threadIdx.x >> 6;
    const int quad = lane >> 4;
    const int l15  = lane & 15;
    const bool lo  = (quad < 2);
    const bool hi8 = (quad & 1) != 0;

    float mask[ETLN];
    int z = mask_and_z(delta_ms, mask);

    // Build B fragments on the fly: V1=[th|tm], V2=[tm|th], V3=[tl|th] along K=32
    int pix[2];
    short8 V1[2], V2[2], V3[2];
#pragma unroll
    for (int g = 0; g < 2; ++g) {
        int p = blockIdx.x * 128 + wv * 32 + g * 16 + l15;
        pix[g] = p;
        float tv[ETLN], s2;
        compute_t(sig + (size_t)p * ETLN, mask, z, tv, &s2);
        ushort hs[ETLN], ms[ETLN], ls[ETLN];
#pragma unroll
        for (int e = 0; e < ETLN; ++e) {
            float r1, r2, dmy;
            hs[e] = bfsplit(tv[e], &r1);
            ms[e] = bfsplit(r1, &r2);
            ls[e] = bfsplit(r2, &dmy);
        }
#pragma unroll
        for (int i = 0; i < 8; ++i) {
            ushort hv = hi8 ? hs[i + 8] : hs[i];
            ushort mv = hi8 ? ms[i + 8] : ms[i];
            ushort lv = hi8 ? ls[i + 8] : ls[i];
            V1[g][i] = (short)(lo ? hv : mv);
            V2[g][i] = (short)(lo ? mv : hv);
            V3[g][i] = (short)(lo ? lv : hv);
        }
    }

    const f32x4 cinit = (f32x4){3.0f, 3.0f, 3.0f, 3.0f};
    uint k1[2], k2[2];
#pragma unroll
    for (int g = 0; g < 2; ++g) { k1[g] = 0xFFFFFFFFu; k2[g] = 0xFFFFFFFFu; }

    const int jbase = blockIdx.y * CT * 16;
    const short8* a1p = (const short8*)A1;
    const short8* a2p = (const short8*)A2;
    // lane's A-frag for tile t: atom row m=l15, k-span quad*8
    int idx0 = (jbase + l15) * 4 + quad;
    short8 a1 = a1p[idx0];
    short8 a2 = a2p[idx0];

    for (int t = 0; t < CT; ++t) {
        int tn = (t + 1 < CT) ? (t + 1) : t;
        int idxn = (jbase + tn * 16 + l15) * 4 + quad;
        short8 na1 = a1p[idxn];
        short8 na2 = a2p[idxn];

        f32x4 acc[2];
#pragma unroll
        for (int g = 0; g < 2; ++g)
            acc[g] = __builtin_amdgcn_mfma_f32_16x16x32_bf16(a1, V1[g], cinit, 0, 0, 0);
#pragma unroll
        for (int g = 0; g < 2; ++g)
            acc[g] = __builtin_amdgcn_mfma_f32_16x16x32_bf16(a1, V2[g], acc[g], 0, 0, 0);
#pragma unroll
        for (int g = 0; g < 2; ++g)
            acc[g] = __builtin_amdgcn_mfma_f32_16x16x32_bf16(a2, V3[g], acc[g], 0, 0, 0);

        const uint jv = (uint)(jbase + t * 16 + quad * 4);  // C row = quad*4 + r
#pragma unroll
        for (int g = 0; g < 2; ++g) {
            uint kk[4];
#pragma unroll
            for (int r = 0; r < 4; ++r)
                kk[r] = ((__float_as_uint(acc[g][r]) << 9) & 0xFFFFF000u) + (jv + r);
            uint m01 = kk[0] < kk[1] ? kk[0] : kk[1];
            uint m23 = kk[2] < kk[3] ? kk[2] : kk[3];
            uint tmin = m01 < m23 ? m01 : m23;
            bool lt = tmin < k1[g];
            uint mn2 = k2[g] < tmin ? k2[g] : tmin;
            k2[g] = lt ? k1[g] : mn2;
            k1[g] = lt ? tmin : k1[g];
        }
        a1 = na1;
        a2 = na2;
    }

    // Cross-quad top-2 merge of sorted key pairs (disjoint atom sets per quad)
#pragma unroll
    for (int g = 0; g < 2; ++g) {
        uint p1 = k1[g], p2 = k2[g];
#pragma unroll
        for (int off = 16; off <= 32; off <<= 1) {
            uint o1 = (uint)__shfl_xor((int)p1, off);
            uint o2 = (uint)__shfl_xor((int)p2, off);
            uint n1 = p1 < o1 ? p1 : o1;
            uint mx = p1 < o1 ? o1 : p1;
            uint mn = p2 < o2 ? p2 : o2;
            p2 = mx < mn ? mx : mn;
            p1 = n1;
        }
        if (lane < 16)
            cand[(size_t)blockIdx.y * NPIX + pix[g]] =
                make_int2((int)(p1 & 0xFFFu), (int)(p2 & 0xFFFu));
    }
}

// merge: exact f32 rescore of 2*SCH candidates per pixel, first-min tie-break
__global__ __launch_bounds__(256) void merge(
        const float* __restrict__ sig, const float* __restrict__ recf,
        const float* __restrict__ t2s, const float* __restrict__ b1s,
        const float* __restrict__ delta_ms, const int2* __restrict__ cand,
        float* __restrict__ out, int SCH) {
    int p = blockIdx.x * 256 + threadIdx.x;
    if (p >= NPIX) return;
    float mask[ETLN];
    int z = mask_and_z(delta_ms, mask);
    float tv[ETLN], s2;
    compute_t(sig + (size_t)p * ETLN, mask, z, tv, &s2);

    float bf = 3.0e38f;
    int bj = 0x7FFFFFFF;
    for (int c = 0; c < SCH; ++c) {
        int2 jj = cand[(size_t)c * NPIX + p];
#pragma unroll
        for (int h = 0; h < 2; ++h) {
            int j = (h == 0) ? jj.x : jj.y;
            const float* rr = recf + (size_t)j * ETLN;
            float f = 0.f;
#pragma unroll
            for (int e = 0; e < ETLN; ++e) f = fmaf(rr[e], tv[e], f);  // d2 - 2*dot
            if (f < bf || (f == bf && j < bj)) { bf = f; bj = j; }
        }
    }
    out[p] = t2s[bj];
    out[NPIX + p] = b1s[bj];
    out[2 * NPIX + p] = sqrtf(fmaxf(bf + s2, 0.0f));
}

extern "C" void kernel_launch(void* const* d_in, const int* in_sizes, int n_in,
                              void* d_out, int out_size, void* d_ws, size_t ws_size,
                              hipStream_t stream) {
    const float* sig    = (const float*)d_in[0];  // [192,192,16]
    const float* db_mag = (const float*)d_in[1];  // [4000,16]
    const float* t2s    = (const float*)d_in[2];  // [4000]
    const float* b1s    = (const float*)d_in[3];  // [4000]
    const float* delta  = (const float*)d_in[4];  // [16]

    char* ws = (char*)d_ws;
    ushort* A1   = (ushort*)(ws + OFF_A1);
    ushort* A2   = (ushort*)(ws + OFF_A2);
    float*  recf = (float*)(ws + OFF_REC);
    int2*   cand = (int2*)(ws + OFF_CAND);

    // SCH must divide 250 tiles evenly: 5 -> 2 -> 1 (ws fallback)
    int SCH = 5;
    if ((size_t)OFF_CAND + (size_t)SCH * NPIX * sizeof(int2) > ws_size) SCH = 2;
    if ((size_t)OFF_CAND + (size_t)SCH * NPIX * sizeof(int2) > ws_size) SCH = 1;
    int CT = TILES_TOTAL / SCH;

    prep<<<(DATOMS + 255) / 256, 256, 0, stream>>>(db_mag, delta, A1, A2, recf);
    dim3 grid(PXB, SCH);
    match<<<grid, 256, 0, stream>>>(A1, A2, sig, delta, cand, CT);
    merge<<<(NPIX + 255) / 256, 256, 0, stream>>>(sig, recf, t2s, b1s, delta, cand,
                                                  (float*)d_out, SCH);
}

// Round 5
// 126.780 us; speedup vs baseline: 1.5450x; 1.1772x over previous
//
#include <hip/hip_runtime.h>
#include <hip/hip_bf16.h>
#include <math.h>

// Problem constants (fixed by setup_inputs)
#define NX 192
#define NY 192
#define NPIX (NX * NY)     // 36864
#define ETLN 16
#define DATOMS 4000
#define TILES_TOTAL 250    // 4000 / 16
#define PXB (NPIX / 128)   // 288 pixel blocks (128 px per block, 32 per wave)

typedef __attribute__((ext_vector_type(8))) short short8;
typedef __attribute__((ext_vector_type(4))) float f32x4;
typedef unsigned short ushort;
typedef unsigned int uint;

// ---- ws layout (bytes) ----
// A1  : 4000 * 32 ushort = 256000   rows [Ah(16)|Am(16)]
// A2  : 4000 * 32 ushort = 256000   rows [Ah(16)|Al(16)]
// REC : 4000 * 16 f32    = 256000   exact f32 atoms (sentinel col = d2)
// CAND: SCH * NPIX int2             per-chunk top-2 candidate indices
#define OFF_A1   0
#define OFF_A2   256000
#define OFF_REC  512000
#define OFF_CAND 768000

__device__ __forceinline__ int mask_and_z(const float* __restrict__ delta_ms,
                                          float* mask) {
    int z = -1;
#pragma unroll
    for (int e = 0; e < ETLN; ++e) {
        float m = (delta_ms[e] * 1e-3f < 1e-3f) ? 1.0f : 0.0f;
        mask[e] = m;
        if (m == 0.0f && z < 0) z = e;
    }
    return z;
}

// bf16 split: returns bf16 bits of x (RN); *rem = x - float(bf16(x)) (exact in f32)
__device__ __forceinline__ ushort bfsplit(float x, float* rem) {
    __hip_bfloat16 h = __float2bfloat16(x);
    *rem = x - __bfloat162float(h);
    union { __hip_bfloat16 h; ushort u; } cv;
    cv.h = h;
    return cv.u;
}

// Two-stage normalize -> t = -2*s, with sentinel t[z]=1 applied via per-element
// SELECT (no dynamic-index store: dynamic alloca indexing defeats SROA and
// gets promoted to LDS -- the R3/R4 16KB LDS_Block_Size smoking gun).
__device__ __forceinline__ void compute_t(const float* __restrict__ row,
                                          const float* mask, int z,
                                          float* tv, float* s2out) {
    float x[ETLN];
    const float4* r4 = (const float4*)row;
#pragma unroll
    for (int q = 0; q < 4; ++q) {
        float4 a = r4[q];
        x[4 * q + 0] = a.x; x[4 * q + 1] = a.y;
        x[4 * q + 2] = a.z; x[4 * q + 3] = a.w;
    }
    float n1s = 0.f;
#pragma unroll
    for (int e = 0; e < ETLN; ++e) n1s += x[e] * x[e];
    float n1 = sqrtf(n1s);
#pragma unroll
    for (int e = 0; e < ETLN; ++e) {
        float y = (n1 > 0.f) ? (x[e] / n1) : 0.f;
        if (!isfinite(y)) y = 0.f;
        x[e] = y * mask[e];
    }
    float n2s = 0.f;
#pragma unroll
    for (int e = 0; e < ETLN; ++e) n2s += x[e] * x[e];
    float n2 = sqrtf(n2s);
    float s2 = 0.f;
#pragma unroll
    for (int e = 0; e < ETLN; ++e) {
        float y = (n2 > 0.f) ? (x[e] / n2) : 0.f;
        if (!isfinite(y)) y = 0.f;
        s2 += y * y;
        float t = -2.0f * y;
        tv[e] = (e == z) ? 1.0f : t;   // select, not dynamic store
    }
    *s2out = s2;
}

// Build one pixel's three B-fragments into NAMED short8s (register-guaranteed).
__device__ __forceinline__ void build_frags(
        const float* __restrict__ sig, int p, const float* mask, int z,
        bool hi8, bool lo, short8* V1, short8* V2, short8* V3) {
    float tv[ETLN], s2;
    compute_t(sig + (size_t)p * ETLN, mask, z, tv, &s2);
    short8 hLo, hHi, mLo, mHi, lLo, lHi;
#pragma unroll
    for (int i = 0; i < 8; ++i) {
        float r1, r2, d;
        ushort ha = bfsplit(tv[i], &r1);
        ushort ma = bfsplit(r1, &r2);
        ushort la = bfsplit(r2, &d);
        ushort hb = bfsplit(tv[i + 8], &r1);
        ushort mb = bfsplit(r1, &r2);
        ushort lb = bfsplit(r2, &d);
        hLo[i] = (short)ha; hHi[i] = (short)hb;
        mLo[i] = (short)ma; mHi[i] = (short)mb;
        lLo[i] = (short)la; lHi[i] = (short)lb;
    }
    short8 hS = hi8 ? hHi : hLo;
    short8 mS = hi8 ? mHi : mLo;
    short8 lS = hi8 ? lHi : lLo;
    *V1 = lo ? hS : mS;   // [th|tm]
    *V2 = lo ? mS : hS;   // [tm|th]
    *V3 = lo ? lS : hS;   // [tl|th]
}

// prep: atoms -> normalized f32 rows (sentinel col = d2) + bf16 split rows
__global__ __launch_bounds__(256) void prep(
        const float* __restrict__ db_mag, const float* __restrict__ delta_ms,
        ushort* __restrict__ A1, ushort* __restrict__ A2,
        float* __restrict__ recf) {
    int t = blockIdx.x * 256 + threadIdx.x;
    if (t >= DATOMS) return;
    float mask[ETLN];
    int z = mask_and_z(delta_ms, mask);

    float v[ETLN];
    float ss = 0.f;
#pragma unroll
    for (int e = 0; e < ETLN; ++e) {
        float x = db_mag[t * ETLN + e] * mask[e];
        v[e] = x;
        ss += x * x;
    }
    float n = sqrtf(ss);
    float d2 = 0.f;
#pragma unroll
    for (int e = 0; e < ETLN; ++e) {
        float y = (n > 0.f) ? (v[e] / n) : 0.f;
        if (!isfinite(y)) y = 0.f;
        v[e] = y;
        d2 += y * y;
    }
#pragma unroll
    for (int e = 0; e < ETLN; ++e) {
        float w = (e == z) ? d2 : v[e];   // sentinel column carries d2 (select)
        recf[t * ETLN + e] = w;
        float r1, r2, dmy;
        ushort hb = bfsplit(w, &r1);
        ushort mb = bfsplit(r1, &r2);
        ushort lb = bfsplit(r2, &dmy);
        A1[t * 32 + e]      = hb;  A1[t * 32 + 16 + e] = mb;
        A2[t * 32 + e]      = hb;  A2[t * 32 + 16 + e] = lb;
    }
}

__device__ __forceinline__ void top2_update(f32x4 acc, uint jv,
                                            uint* k1, uint* k2) {
    // f = 3 + d2 - 2*dot in (2,4): one IEEE exponent -> mantissa-bit order =
    // value order. key = top-20 mantissa bits <<12 | atom index (12 bits).
    uint kk0 = ((__float_as_uint(acc[0]) << 9) & 0xFFFFF000u) + jv;
    uint kk1 = ((__float_as_uint(acc[1]) << 9) & 0xFFFFF000u) + jv + 1u;
    uint kk2 = ((__float_as_uint(acc[2]) << 9) & 0xFFFFF000u) + jv + 2u;
    uint kk3 = ((__float_as_uint(acc[3]) << 9) & 0xFFFFF000u) + jv + 3u;
    uint m01 = kk0 < kk1 ? kk0 : kk1;
    uint m23 = kk2 < kk3 ? kk2 : kk3;
    uint tmin = m01 < m23 ? m01 : m23;
    bool lt = tmin < *k1;
    uint mn2 = *k2 < tmin ? *k2 : tmin;
    *k2 = lt ? *k1 : mn2;
    *k1 = lt ? tmin : *k1;
}

// match: 32 pixels/wave x one atom chunk; split-bf16 MFMA, packed-key top-2.
// All K-loop state in NAMED scalars/vectors -- no arrays (see R4 post-mortem).
__global__ __launch_bounds__(256, 3) void match(
        const ushort* __restrict__ A1, const ushort* __restrict__ A2,
        const float* __restrict__ sig, const float* __restrict__ delta_ms,
        int2* __restrict__ cand, int CT) {
    const int lane = threadIdx.x & 63;
    const int wv   = threadIdx.x >> 6;
    const int quad = lane >> 4;
    const int l15  = lane & 15;
    const bool lo  = (quad < 2);
    const bool hi8 = (quad & 1) != 0;

    float mask[ETLN];
    int z = mask_and_z(delta_ms, mask);

    const int pA = blockIdx.x * 128 + wv * 32 + l15;
    const int pB = pA + 16;
    short8 V1A, V2A, V3A, V1B, V2B, V3B;
    build_frags(sig, pA, mask, z, hi8, lo, &V1A, &V2A, &V3A);
    build_frags(sig, pB, mask, z, hi8, lo, &V1B, &V2B, &V3B);

    uint k1A = 0xFFFFFFFFu, k2A = 0xFFFFFFFFu;
    uint k1B = 0xFFFFFFFFu, k2B = 0xFFFFFFFFu;

    const int jbase = blockIdx.y * CT * 16;
    const short8* a1p = (const short8*)A1;
    const short8* a2p = (const short8*)A2;
    // lane's A-frag for tile t: atom row m=l15, k-span quad*8
    int idx0 = (jbase + l15) * 4 + quad;
    short8 a1 = a1p[idx0];
    short8 a2 = a2p[idx0];
    const f32x4 cinit = (f32x4){3.0f, 3.0f, 3.0f, 3.0f};

    for (int t = 0; t < CT; ++t) {
        int tn = (t + 1 < CT) ? (t + 1) : t;
        int idxn = (jbase + tn * 16 + l15) * 4 + quad;
        short8 na1 = a1p[idxn];
        short8 na2 = a2p[idxn];

        f32x4 accA = __builtin_amdgcn_mfma_f32_16x16x32_bf16(a1, V1A, cinit, 0, 0, 0);
        f32x4 accB = __builtin_amdgcn_mfma_f32_16x16x32_bf16(a1, V1B, cinit, 0, 0, 0);
        accA = __builtin_amdgcn_mfma_f32_16x16x32_bf16(a1, V2A, accA, 0, 0, 0);
        accB = __builtin_amdgcn_mfma_f32_16x16x32_bf16(a1, V2B, accB, 0, 0, 0);
        accA = __builtin_amdgcn_mfma_f32_16x16x32_bf16(a2, V3A, accA, 0, 0, 0);
        accB = __builtin_amdgcn_mfma_f32_16x16x32_bf16(a2, V3B, accB, 0, 0, 0);

        const uint jv = (uint)(jbase + t * 16 + quad * 4);  // C row = quad*4 + r
        top2_update(accA, jv, &k1A, &k2A);
        top2_update(accB, jv, &k1B, &k2B);
        a1 = na1;
        a2 = na2;
    }

    // Cross-quad top-2 merge of sorted key pairs (disjoint atom sets per quad)
#pragma unroll
    for (int g = 0; g < 2; ++g) {
        uint p1 = g ? k1B : k1A;
        uint p2 = g ? k2B : k2A;
#pragma unroll
        for (int off = 16; off <= 32; off <<= 1) {
            uint o1 = (uint)__shfl_xor((int)p1, off);
            uint o2 = (uint)__shfl_xor((int)p2, off);
            uint n1 = p1 < o1 ? p1 : o1;
            uint mx = p1 < o1 ? o1 : p1;
            uint mn = p2 < o2 ? p2 : o2;
            p2 = mx < mn ? mx : mn;
            p1 = n1;
        }
        if (lane < 16)
            cand[(size_t)blockIdx.y * NPIX + (g ? pB : pA)] =
                make_int2((int)(p1 & 0xFFFu), (int)(p2 & 0xFFFu));
    }
}

// merge: exact f32 rescore of 2*SCH candidates per pixel, first-min tie-break
__global__ __launch_bounds__(256) void merge(
        const float* __restrict__ sig, const float* __restrict__ recf,
        const float* __restrict__ t2s, const float* __restrict__ b1s,
        const float* __restrict__ delta_ms, const int2* __restrict__ cand,
        float* __restrict__ out, int SCH) {
    int p = blockIdx.x * 256 + threadIdx.x;
    if (p >= NPIX) return;
    float mask[ETLN];
    int z = mask_and_z(delta_ms, mask);
    float tv[ETLN], s2;
    compute_t(sig + (size_t)p * ETLN, mask, z, tv, &s2);

    float bf = 3.0e38f;
    int bj = 0x7FFFFFFF;
    for (int c = 0; c < SCH; ++c) {
        int2 jj = cand[(size_t)c * NPIX + p];
#pragma unroll
        for (int h = 0; h < 2; ++h) {
            int j = (h == 0) ? jj.x : jj.y;
            const float* rr = recf + (size_t)j * ETLN;
            float f = 0.f;
#pragma unroll
            for (int e = 0; e < ETLN; ++e) f = fmaf(rr[e], tv[e], f);  // d2 - 2*dot
            if (f < bf || (f == bf && j < bj)) { bf = f; bj = j; }
        }
    }
    out[p] = t2s[bj];
    out[NPIX + p] = b1s[bj];
    out[2 * NPIX + p] = sqrtf(fmaxf(bf + s2, 0.0f));
}

extern "C" void kernel_launch(void* const* d_in, const int* in_sizes, int n_in,
                              void* d_out, int out_size, void* d_ws, size_t ws_size,
                              hipStream_t stream) {
    const float* sig    = (const float*)d_in[0];  // [192,192,16]
    const float* db_mag = (const float*)d_in[1];  // [4000,16]
    const float* t2s    = (const float*)d_in[2];  // [4000]
    const float* b1s    = (const float*)d_in[3];  // [4000]
    const float* delta  = (const float*)d_in[4];  // [16]

    char* ws = (char*)d_ws;
    ushort* A1   = (ushort*)(ws + OFF_A1);
    ushort* A2   = (ushort*)(ws + OFF_A2);
    float*  recf = (float*)(ws + OFF_REC);
    int2*   cand = (int2*)(ws + OFF_CAND);

    // SCH must divide 250 tiles evenly: 5 -> 2 -> 1 (ws fallback)
    int SCH = 5;
    if ((size_t)OFF_CAND + (size_t)SCH * NPIX * sizeof(int2) > ws_size) SCH = 2;
    if ((size_t)OFF_CAND + (size_t)SCH * NPIX * sizeof(int2) > ws_size) SCH = 1;
    int CT = TILES_TOTAL / SCH;

    prep<<<(DATOMS + 255) / 256, 256, 0, stream>>>(db_mag, delta, A1, A2, recf);
    dim3 grid(PXB, SCH);
    match<<<grid, 256, 0, stream>>>(A1, A2, sig, delta, cand, CT);
    merge<<<(NPIX + 255) / 256, 256, 0, stream>>>(sig, recf, t2s, b1s, delta, cand,
                                                  (float*)d_out, SCH);
}

// Round 6
// 112.906 us; speedup vs baseline: 1.7348x; 1.1229x over previous
//
#include <hip/hip_runtime.h>
#include <hip/hip_bf16.h>
#include <math.h>

// Problem constants (fixed by setup_inputs)
#define NX 192
#define NY 192
#define NPIX (NX * NY)     // 36864
#define ETLN 16
#define DATOMS 4000
#define TILES_TOTAL 250    // 4000 / 16
#define PXB (NPIX / 128)   // 288 pixel blocks (128 px per block, 32 per wave)

typedef __attribute__((ext_vector_type(8))) short short8;
typedef __attribute__((ext_vector_type(4))) float f32x4;
typedef unsigned short ushort;
typedef unsigned int uint;

// ---- ws layout (bytes) ----
// A1  : 4000 * 32 ushort = 256000   rows [Ah(16)|Am(16)]  (2-way split; no A2)
// REC : 4000 * 16 f32    = 256000   exact f32 atoms (sentinel col = d2)
// CAND: SCH * NPIX int2             per-chunk top-2 candidate indices
#define OFF_A1   0
#define OFF_REC  256000
#define OFF_CAND 512000

__device__ __forceinline__ int mask_and_z(const float* __restrict__ delta_ms,
                                          float* mask) {
    int z = -1;
#pragma unroll
    for (int e = 0; e < ETLN; ++e) {
        float m = (delta_ms[e] * 1e-3f < 1e-3f) ? 1.0f : 0.0f;
        mask[e] = m;
        if (m == 0.0f && z < 0) z = e;
    }
    return z;
}

// bf16 split: returns bf16 bits of x (RN); *rem = x - float(bf16(x)) (exact in f32)
__device__ __forceinline__ ushort bfsplit(float x, float* rem) {
    __hip_bfloat16 h = __float2bfloat16(x);
    *rem = x - __bfloat162float(h);
    union { __hip_bfloat16 h; ushort u; } cv;
    cv.h = h;
    return cv.u;
}

// Two-stage normalize -> t = -2*s, sentinel t[z]=1 via per-element SELECT
// (dynamic-index alloca stores get promoted to LDS -- R4 lesson).
__device__ __forceinline__ void compute_t(const float* __restrict__ row,
                                          const float* mask, int z,
                                          float* tv, float* s2out) {
    float x[ETLN];
    const float4* r4 = (const float4*)row;
#pragma unroll
    for (int q = 0; q < 4; ++q) {
        float4 a = r4[q];
        x[4 * q + 0] = a.x; x[4 * q + 1] = a.y;
        x[4 * q + 2] = a.z; x[4 * q + 3] = a.w;
    }
    float n1s = 0.f;
#pragma unroll
    for (int e = 0; e < ETLN; ++e) n1s += x[e] * x[e];
    float n1 = sqrtf(n1s);
#pragma unroll
    for (int e = 0; e < ETLN; ++e) {
        float y = (n1 > 0.f) ? (x[e] / n1) : 0.f;
        if (!isfinite(y)) y = 0.f;
        x[e] = y * mask[e];
    }
    float n2s = 0.f;
#pragma unroll
    for (int e = 0; e < ETLN; ++e) n2s += x[e] * x[e];
    float n2 = sqrtf(n2s);
    float s2 = 0.f;
#pragma unroll
    for (int e = 0; e < ETLN; ++e) {
        float y = (n2 > 0.f) ? (x[e] / n2) : 0.f;
        if (!isfinite(y)) y = 0.f;
        s2 += y * y;
        float t = -2.0f * y;
        tv[e] = (e == z) ? 1.0f : t;   // select, not dynamic store
    }
    *s2out = s2;
}

// Build one pixel's two B-fragments (2-way split) into NAMED short8s.
__device__ __forceinline__ void build_frags(
        const float* __restrict__ sig, int p, const float* mask, int z,
        bool hi8, bool lo, short8* V1, short8* V2) {
    float tv[ETLN], s2;
    compute_t(sig + (size_t)p * ETLN, mask, z, tv, &s2);
    short8 hLo, hHi, mLo, mHi;
#pragma unroll
    for (int i = 0; i < 8; ++i) {
        float r1, d;
        ushort ha = bfsplit(tv[i], &r1);
        ushort ma = bfsplit(r1, &d);
        ushort hb = bfsplit(tv[i + 8], &r1);
        ushort mb = bfsplit(r1, &d);
        hLo[i] = (short)ha; hHi[i] = (short)hb;
        mLo[i] = (short)ma; mHi[i] = (short)mb;
    }
    short8 hS = hi8 ? hHi : hLo;
    short8 mS = hi8 ? mHi : mLo;
    *V1 = lo ? hS : mS;   // [th|tm]
    *V2 = lo ? mS : hS;   // [tm|th]
}

// prep: atoms -> normalized f32 rows (sentinel col = d2) + 2-way bf16 split rows
__global__ __launch_bounds__(256) void prep(
        const float* __restrict__ db_mag, const float* __restrict__ delta_ms,
        ushort* __restrict__ A1, float* __restrict__ recf) {
    int t = blockIdx.x * 256 + threadIdx.x;
    if (t >= DATOMS) return;
    float mask[ETLN];
    int z = mask_and_z(delta_ms, mask);

    float v[ETLN];
    float ss = 0.f;
#pragma unroll
    for (int e = 0; e < ETLN; ++e) {
        float x = db_mag[t * ETLN + e] * mask[e];
        v[e] = x;
        ss += x * x;
    }
    float n = sqrtf(ss);
    float d2 = 0.f;
#pragma unroll
    for (int e = 0; e < ETLN; ++e) {
        float y = (n > 0.f) ? (v[e] / n) : 0.f;
        if (!isfinite(y)) y = 0.f;
        v[e] = y;
        d2 += y * y;
    }
#pragma unroll
    for (int e = 0; e < ETLN; ++e) {
        float w = (e == z) ? d2 : v[e];   // sentinel column carries d2 (select)
        recf[t * ETLN + e] = w;
        float r1, dmy;
        ushort hb = bfsplit(w, &r1);
        ushort mb = bfsplit(r1, &dmy);
        A1[t * 32 + e]      = hb;
        A1[t * 32 + 16 + e] = mb;
    }
}

// f = 3 + d2 - 2*dot in (2,4): single IEEE exponent -> mantissa bits are
// order-preserving. key = top-20 mantissa bits <<12 | atom index (12 bits).
// jr = jbase + t*16 + quad*4 (multiple-of-16 base | lane offset).
__device__ __forceinline__ void top2_update(f32x4 acc, uint jr,
                                            uint* k1, uint* k2) {
    uint kk0 = ((__float_as_uint(acc[0]) << 9) & 0xFFFFF000u) | (jr + 0u);
    uint kk1 = ((__float_as_uint(acc[1]) << 9) & 0xFFFFF000u) | (jr + 1u);
    uint kk2 = ((__float_as_uint(acc[2]) << 9) & 0xFFFFF000u) | (jr + 2u);
    uint kk3 = ((__float_as_uint(acc[3]) << 9) & 0xFFFFF000u) | (jr + 3u);
    uint m01 = kk0 < kk1 ? kk0 : kk1;
    uint m23 = kk2 < kk3 ? kk2 : kk3;
    uint tmin = m01 < m23 ? m01 : m23;
    bool lt = tmin < *k1;
    uint mn2 = *k2 < tmin ? *k2 : tmin;
    *k2 = lt ? *k1 : mn2;
    *k1 = lt ? tmin : *k1;
}

// match: 32 pixels/wave x one atom chunk; 2-way split bf16 MFMA (2 per tile per
// pixel-group), unroll x2 over tiles, packed-key top-2. All loop state in
// NAMED registers (R4 lesson: no arrays, no dynamic indexing).
__global__ __launch_bounds__(256, 6) void match(
        const ushort* __restrict__ A1, const float* __restrict__ sig,
        const float* __restrict__ delta_ms, int2* __restrict__ cand, int CT) {
    const int lane = threadIdx.x & 63;
    const int wv   = threadIdx.x >> 6;
    const int quad = lane >> 4;
    const int l15  = lane & 15;
    const bool lo  = (quad < 2);
    const bool hi8 = (quad & 1) != 0;

    float mask[ETLN];
    int z = mask_and_z(delta_ms, mask);

    const int pA = blockIdx.x * 128 + wv * 32 + l15;
    const int pB = pA + 16;
    short8 V1A, V2A, V1B, V2B;
    build_frags(sig, pA, mask, z, hi8, lo, &V1A, &V2A);
    build_frags(sig, pB, mask, z, hi8, lo, &V1B, &V2B);

    uint k1A = 0xFFFFFFFFu, k2A = 0xFFFFFFFFu;
    uint k1B = 0xFFFFFFFFu, k2B = 0xFFFFFFFFu;

    const int jbase = blockIdx.y * CT * 16;
    const short8* ap = (const short8*)A1;
    // lane's A-frag for tile t: atom row m=l15, k-span quad*8
    const int ib = (jbase + l15) * 4 + quad;   // + t*64 per tile
    short8 a0 = ap[ib];
    short8 a1 = ap[ib + 64];
    const f32x4 cinit = (f32x4){3.0f, 3.0f, 3.0f, 3.0f};

    for (int t = 0; t < CT; t += 2) {
        int pf = (t + 2 < CT) ? (t + 2) : t;   // clamp: harmless reload at tail
        short8 na0 = ap[ib + pf * 64];
        short8 na1 = ap[ib + pf * 64 + 64];

        f32x4 acc00 = __builtin_amdgcn_mfma_f32_16x16x32_bf16(a0, V1A, cinit, 0, 0, 0);
        f32x4 acc01 = __builtin_amdgcn_mfma_f32_16x16x32_bf16(a0, V1B, cinit, 0, 0, 0);
        f32x4 acc10 = __builtin_amdgcn_mfma_f32_16x16x32_bf16(a1, V1A, cinit, 0, 0, 0);
        f32x4 acc11 = __builtin_amdgcn_mfma_f32_16x16x32_bf16(a1, V1B, cinit, 0, 0, 0);
        acc00 = __builtin_amdgcn_mfma_f32_16x16x32_bf16(a0, V2A, acc00, 0, 0, 0);
        acc01 = __builtin_amdgcn_mfma_f32_16x16x32_bf16(a0, V2B, acc01, 0, 0, 0);
        acc10 = __builtin_amdgcn_mfma_f32_16x16x32_bf16(a1, V2A, acc10, 0, 0, 0);
        acc11 = __builtin_amdgcn_mfma_f32_16x16x32_bf16(a1, V2B, acc11, 0, 0, 0);

        const uint jr0 = (uint)(jbase + t * 16 + quad * 4);        // C row = quad*4+r
        const uint jr1 = jr0 + 16u;
        top2_update(acc00, jr0, &k1A, &k2A);
        top2_update(acc01, jr0, &k1B, &k2B);
        top2_update(acc10, jr1, &k1A, &k2A);
        top2_update(acc11, jr1, &k1B, &k2B);
        a0 = na0;
        a1 = na1;
    }

    // Cross-quad top-2 merge of sorted key pairs (disjoint atom sets per quad)
#pragma unroll
    for (int g = 0; g < 2; ++g) {
        uint p1 = g ? k1B : k1A;
        uint p2 = g ? k2B : k2A;
#pragma unroll
        for (int off = 16; off <= 32; off <<= 1) {
            uint o1 = (uint)__shfl_xor((int)p1, off);
            uint o2 = (uint)__shfl_xor((int)p2, off);
            uint n1 = p1 < o1 ? p1 : o1;
            uint mx = p1 < o1 ? o1 : p1;
            uint mn = p2 < o2 ? p2 : o2;
            p2 = mx < mn ? mx : mn;
            p1 = n1;
        }
        if (lane < 16)
            cand[(size_t)blockIdx.y * NPIX + (g ? pB : pA)] =
                make_int2((int)(p1 & 0xFFFu), (int)(p2 & 0xFFFu));
    }
}

// merge: exact f32 rescore of 2*SCH candidates per pixel, first-min tie-break
__global__ __launch_bounds__(256) void merge(
        const float* __restrict__ sig, const float* __restrict__ recf,
        const float* __restrict__ t2s, const float* __restrict__ b1s,
        const float* __restrict__ delta_ms, const int2* __restrict__ cand,
        float* __restrict__ out, int SCH) {
    int p = blockIdx.x * 256 + threadIdx.x;
    if (p >= NPIX) return;
    float mask[ETLN];
    int z = mask_and_z(delta_ms, mask);
    float tv[ETLN], s2;
    compute_t(sig + (size_t)p * ETLN, mask, z, tv, &s2);

    float bf = 3.0e38f;
    int bj = 0x7FFFFFFF;
    for (int c = 0; c < SCH; ++c) {
        int2 jj = cand[(size_t)c * NPIX + p];
#pragma unroll
        for (int h = 0; h < 2; ++h) {
            int j = (h == 0) ? jj.x : jj.y;
            const float* rr = recf + (size_t)j * ETLN;
            float f = 0.f;
#pragma unroll
            for (int e = 0; e < ETLN; ++e) f = fmaf(rr[e], tv[e], f);  // d2 - 2*dot
            if (f < bf || (f == bf && j < bj)) { bf = f; bj = j; }
        }
    }
    out[p] = t2s[bj];
    out[NPIX + p] = b1s[bj];
    out[2 * NPIX + p] = sqrtf(fmaxf(bf + s2, 0.0f));
}

extern "C" void kernel_launch(void* const* d_in, const int* in_sizes, int n_in,
                              void* d_out, int out_size, void* d_ws, size_t ws_size,
                              hipStream_t stream) {
    const float* sig    = (const float*)d_in[0];  // [192,192,16]
    const float* db_mag = (const float*)d_in[1];  // [4000,16]
    const float* t2s    = (const float*)d_in[2];  // [4000]
    const float* b1s    = (const float*)d_in[3];  // [4000]
    const float* delta  = (const float*)d_in[4];  // [16]

    char* ws = (char*)d_ws;
    ushort* A1   = (ushort*)(ws + OFF_A1);
    float*  recf = (float*)(ws + OFF_REC);
    int2*   cand = (int2*)(ws + OFF_CAND);

    // SCH must give an EVEN tile count (unroll x2): 5 -> CT=50; fallback 1 -> 250
    int SCH = 5;
    if ((size_t)OFF_CAND + (size_t)SCH * NPIX * sizeof(int2) > ws_size) SCH = 1;
    int CT = TILES_TOTAL / SCH;

    prep<<<(DATOMS + 255) / 256, 256, 0, stream>>>(db_mag, delta, A1, recf);
    dim3 grid(PXB, SCH);
    match<<<grid, 256, 0, stream>>>(A1, sig, delta, cand, CT);
    merge<<<(NPIX + 255) / 256, 256, 0, stream>>>(sig, recf, t2s, b1s, delta, cand,
                                                  (float*)d_out, SCH);
}

// Round 7
// 105.672 us; speedup vs baseline: 1.8536x; 1.0685x over previous
//
#include <hip/hip_runtime.h>
#include <hip/hip_bf16.h>
#include <math.h>

// Problem constants (fixed by setup_inputs)
#define NX 192
#define NY 192
#define NPIX (NX * NY)     // 36864
#define ETLN 16
#define DATOMS 4000
#define TILES_TOTAL 250    // 4000 / 16
#define PXB (NPIX / 128)   // 288 pixel blocks (128 px per block, 32 per wave)

typedef __attribute__((ext_vector_type(8))) short short8;
typedef __attribute__((ext_vector_type(4))) float f32x4;
typedef unsigned short ushort;
typedef unsigned int uint;

// ---- ws layout (bytes) ----
// A1  : 4000 * 32 ushort = 256000   rows [Ah(16)|Am(16)]  (2-way split)
// REC : 4000 * 16 f32    = 256000   exact f32 atoms (sentinel col = d2)
// CAND: SCH * NPIX int2             per-chunk top-2 candidate indices
#define OFF_A1   0
#define OFF_REC  256000
#define OFF_CAND 512000

__device__ __forceinline__ int mask_and_z(const float* __restrict__ delta_ms,
                                          float* mask) {
    int z = -1;
#pragma unroll
    for (int e = 0; e < ETLN; ++e) {
        float m = (delta_ms[e] * 1e-3f < 1e-3f) ? 1.0f : 0.0f;
        mask[e] = m;
        if (m == 0.0f && z < 0) z = e;
    }
    return z;
}

// bf16 split: returns bf16 bits of x (RN); *rem = x - float(bf16(x)) (exact in f32)
__device__ __forceinline__ ushort bfsplit(float x, float* rem) {
    __hip_bfloat16 h = __float2bfloat16(x);
    *rem = x - __bfloat162float(h);
    union { __hip_bfloat16 h; ushort u; } cv;
    cv.h = h;
    return cv.u;
}

// Two-stage normalize -> t = -2*s, sentinel t[z]=1 via per-element SELECT.
// Reciprocal-multiply form: 2 divides total (not 32). n==0 -> inv=0 reproduces
// nan_to_num(x/0 -> 0); n>0 is >=1e-7 for uniform inputs so inv is finite and
// the per-element isfinite guards are dead -- dropped.
__device__ __forceinline__ void compute_t(const float* __restrict__ row,
                                          const float* mask, int z,
                                          float* tv, float* s2out) {
    float x[ETLN];
    const float4* r4 = (const float4*)row;
#pragma unroll
    for (int q = 0; q < 4; ++q) {
        float4 a = r4[q];
        x[4 * q + 0] = a.x; x[4 * q + 1] = a.y;
        x[4 * q + 2] = a.z; x[4 * q + 3] = a.w;
    }
    float n1s = 0.f;
#pragma unroll
    for (int e = 0; e < ETLN; ++e) n1s += x[e] * x[e];
    float n1 = sqrtf(n1s);
    float inv1 = (n1 > 0.f) ? (1.0f / n1) : 0.f;
#pragma unroll
    for (int e = 0; e < ETLN; ++e) x[e] = x[e] * inv1 * mask[e];
    float n2s = 0.f;
#pragma unroll
    for (int e = 0; e < ETLN; ++e) n2s += x[e] * x[e];
    float n2 = sqrtf(n2s);
    float inv2 = (n2 > 0.f) ? (1.0f / n2) : 0.f;
    float s2 = 0.f;
#pragma unroll
    for (int e = 0; e < ETLN; ++e) {
        float y = x[e] * inv2;
        s2 += y * y;
        float t = -2.0f * y;
        tv[e] = (e == z) ? 1.0f : t;   // select, not dynamic store (R4 lesson)
    }
    *s2out = s2;
}

// Build one pixel's two B-fragments (2-way split) into NAMED short8s.
__device__ __forceinline__ void build_frags(
        const float* __restrict__ sig, int p, const float* mask, int z,
        bool hi8, bool lo, short8* V1, short8* V2) {
    float tv[ETLN], s2;
    compute_t(sig + (size_t)p * ETLN, mask, z, tv, &s2);
    short8 hLo, hHi, mLo, mHi;
#pragma unroll
    for (int i = 0; i < 8; ++i) {
        float r1, d;
        ushort ha = bfsplit(tv[i], &r1);
        ushort ma = bfsplit(r1, &d);
        ushort hb = bfsplit(tv[i + 8], &r1);
        ushort mb = bfsplit(r1, &d);
        hLo[i] = (short)ha; hHi[i] = (short)hb;
        mLo[i] = (short)ma; mHi[i] = (short)mb;
    }
    short8 hS = hi8 ? hHi : hLo;
    short8 mS = hi8 ? mHi : mLo;
    *V1 = lo ? hS : mS;   // [th|tm]
    *V2 = lo ? mS : hS;   // [tm|th]
}

// prep: atoms -> normalized f32 rows (sentinel col = d2) + 2-way bf16 split rows
__global__ __launch_bounds__(256) void prep(
        const float* __restrict__ db_mag, const float* __restrict__ delta_ms,
        ushort* __restrict__ A1, float* __restrict__ recf) {
    int t = blockIdx.x * 256 + threadIdx.x;
    if (t >= DATOMS) return;
    float mask[ETLN];
    int z = mask_and_z(delta_ms, mask);

    float v[ETLN];
    float ss = 0.f;
#pragma unroll
    for (int e = 0; e < ETLN; ++e) {
        float x = db_mag[t * ETLN + e] * mask[e];
        v[e] = x;
        ss += x * x;
    }
    float n = sqrtf(ss);
    float inv = (n > 0.f) ? (1.0f / n) : 0.f;
    float d2 = 0.f;
#pragma unroll
    for (int e = 0; e < ETLN; ++e) {
        float y = v[e] * inv;
        v[e] = y;
        d2 += y * y;
    }
#pragma unroll
    for (int e = 0; e < ETLN; ++e) {
        float w = (e == z) ? d2 : v[e];   // sentinel column carries d2 (select)
        recf[t * ETLN + e] = w;
        float r1, dmy;
        ushort hb = bfsplit(w, &r1);
        ushort mb = bfsplit(r1, &dmy);
        A1[t * 32 + e]      = hb;
        A1[t * 32 + 16 + e] = mb;
    }
}

// f = 3 + d2 - 2*dot in (2,4): single IEEE exponent -> mantissa bits are
// order-preserving. key = top-20 mantissa bits <<12 | atom index (12 bits).
__device__ __forceinline__ void top2_update(f32x4 acc, uint jr,
                                            uint* k1, uint* k2) {
    uint kk0 = ((__float_as_uint(acc[0]) << 9) & 0xFFFFF000u) | (jr + 0u);
    uint kk1 = ((__float_as_uint(acc[1]) << 9) & 0xFFFFF000u) | (jr + 1u);
    uint kk2 = ((__float_as_uint(acc[2]) << 9) & 0xFFFFF000u) | (jr + 2u);
    uint kk3 = ((__float_as_uint(acc[3]) << 9) & 0xFFFFF000u) | (jr + 3u);
    uint m01 = kk0 < kk1 ? kk0 : kk1;
    uint m23 = kk2 < kk3 ? kk2 : kk3;
    uint tmin = m01 < m23 ? m01 : m23;
    bool lt = tmin < *k1;
    uint mn2 = *k2 < tmin ? *k2 : tmin;
    *k2 = lt ? *k1 : mn2;
    *k1 = lt ? tmin : *k1;
}

// match: 32 pixels/wave x one atom chunk; 2-way split bf16 MFMA, unroll x2,
// packed-key top-2. asm "+v" pins force arch-VGPR residency on the loop's
// working set (R5/R6: allocator homed frags/acc in AGPRs and shuttled
// v_accvgpr_read/write every iter -- ~160 junk VALU/iter).
__global__ __launch_bounds__(256, 4) void match(
        const ushort* __restrict__ A1, const float* __restrict__ sig,
        const float* __restrict__ delta_ms, int2* __restrict__ cand, int CT) {
    const int lane = threadIdx.x & 63;
    const int wv   = threadIdx.x >> 6;
    const int quad = lane >> 4;
    const int l15  = lane & 15;
    const bool lo  = (quad < 2);
    const bool hi8 = (quad & 1) != 0;

    float mask[ETLN];
    int z = mask_and_z(delta_ms, mask);

    const int pA = blockIdx.x * 128 + wv * 32 + l15;
    const int pB = pA + 16;
    short8 V1A, V2A, V1B, V2B;
    build_frags(sig, pA, mask, z, hi8, lo, &V1A, &V2A);
    build_frags(sig, pB, mask, z, hi8, lo, &V1B, &V2B);
    asm("" : "+v"(V1A), "+v"(V2A), "+v"(V1B), "+v"(V2B));

    uint k1A = 0xFFFFFFFFu, k2A = 0xFFFFFFFFu;
    uint k1B = 0xFFFFFFFFu, k2B = 0xFFFFFFFFu;

    const int jbase = blockIdx.y * CT * 16;
    const short8* ap = (const short8*)A1;
    // lane's A-frag for tile t: atom row m=l15, k-span quad*8
    const int ib = (jbase + l15) * 4 + quad;   // + t*64 per tile
    short8 a0 = ap[ib];
    short8 a1 = ap[ib + 64];
    const f32x4 cinit = (f32x4){3.0f, 3.0f, 3.0f, 3.0f};

    for (int t = 0; t < CT; t += 2) {
        int pf = (t + 2 < CT) ? (t + 2) : t;   // clamp: harmless reload at tail
        short8 na0 = ap[ib + pf * 64];
        short8 na1 = ap[ib + pf * 64 + 64];
        asm("" : "+v"(a0), "+v"(a1));

        f32x4 acc00 = __builtin_amdgcn_mfma_f32_16x16x32_bf16(a0, V1A, cinit, 0, 0, 0);
        f32x4 acc01 = __builtin_amdgcn_mfma_f32_16x16x32_bf16(a0, V1B, cinit, 0, 0, 0);
        f32x4 acc10 = __builtin_amdgcn_mfma_f32_16x16x32_bf16(a1, V1A, cinit, 0, 0, 0);
        f32x4 acc11 = __builtin_amdgcn_mfma_f32_16x16x32_bf16(a1, V1B, cinit, 0, 0, 0);
        acc00 = __builtin_amdgcn_mfma_f32_16x16x32_bf16(a0, V2A, acc00, 0, 0, 0);
        acc01 = __builtin_amdgcn_mfma_f32_16x16x32_bf16(a0, V2B, acc01, 0, 0, 0);
        acc10 = __builtin_amdgcn_mfma_f32_16x16x32_bf16(a1, V2A, acc10, 0, 0, 0);
        acc11 = __builtin_amdgcn_mfma_f32_16x16x32_bf16(a1, V2B, acc11, 0, 0, 0);
        asm("" : "+v"(acc00), "+v"(acc01), "+v"(acc10), "+v"(acc11));

        const uint jr0 = (uint)(jbase + t * 16 + quad * 4);        // C row = quad*4+r
        const uint jr1 = jr0 + 16u;
        top2_update(acc00, jr0, &k1A, &k2A);
        top2_update(acc01, jr0, &k1B, &k2B);
        top2_update(acc10, jr1, &k1A, &k2A);
        top2_update(acc11, jr1, &k1B, &k2B);
        a0 = na0;
        a1 = na1;
    }

    // Cross-quad top-2 merge of sorted key pairs (disjoint atom sets per quad)
#pragma unroll
    for (int g = 0; g < 2; ++g) {
        uint p1 = g ? k1B : k1A;
        uint p2 = g ? k2B : k2A;
#pragma unroll
        for (int off = 16; off <= 32; off <<= 1) {
            uint o1 = (uint)__shfl_xor((int)p1, off);
            uint o2 = (uint)__shfl_xor((int)p2, off);
            uint n1 = p1 < o1 ? p1 : o1;
            uint mx = p1 < o1 ? o1 : p1;
            uint mn = p2 < o2 ? p2 : o2;
            p2 = mx < mn ? mx : mn;
            p1 = n1;
        }
        if (lane < 16)
            cand[(size_t)blockIdx.y * NPIX + (g ? pB : pA)] =
                make_int2((int)(p1 & 0xFFFu), (int)(p2 & 0xFFFu));
    }
}

// merge: exact f32 rescore of 2*SCH candidates per pixel, first-min tie-break
__global__ __launch_bounds__(256) void merge(
        const float* __restrict__ sig, const float* __restrict__ recf,
        const float* __restrict__ t2s, const float* __restrict__ b1s,
        const float* __restrict__ delta_ms, const int2* __restrict__ cand,
        float* __restrict__ out, int SCH) {
    int p = blockIdx.x * 256 + threadIdx.x;
    if (p >= NPIX) return;
    float mask[ETLN];
    int z = mask_and_z(delta_ms, mask);
    float tv[ETLN], s2;
    compute_t(sig + (size_t)p * ETLN, mask, z, tv, &s2);

    float bf = 3.0e38f;
    int bj = 0x7FFFFFFF;
    for (int c = 0; c < SCH; ++c) {
        int2 jj = cand[(size_t)c * NPIX + p];
#pragma unroll
        for (int h = 0; h < 2; ++h) {
            int j = (h == 0) ? jj.x : jj.y;
            const float* rr = recf + (size_t)j * ETLN;
            float f = 0.f;
#pragma unroll
            for (int e = 0; e < ETLN; ++e) f = fmaf(rr[e], tv[e], f);  // d2 - 2*dot
            if (f < bf || (f == bf && j < bj)) { bf = f; bj = j; }
        }
    }
    out[p] = t2s[bj];
    out[NPIX + p] = b1s[bj];
    out[2 * NPIX + p] = sqrtf(fmaxf(bf + s2, 0.0f));
}

extern "C" void kernel_launch(void* const* d_in, const int* in_sizes, int n_in,
                              void* d_out, int out_size, void* d_ws, size_t ws_size,
                              hipStream_t stream) {
    const float* sig    = (const float*)d_in[0];  // [192,192,16]
    const float* db_mag = (const float*)d_in[1];  // [4000,16]
    const float* t2s    = (const float*)d_in[2];  // [4000]
    const float* b1s    = (const float*)d_in[3];  // [4000]
    const float* delta  = (const float*)d_in[4];  // [16]

    char* ws = (char*)d_ws;
    ushort* A1   = (ushort*)(ws + OFF_A1);
    float*  recf = (float*)(ws + OFF_REC);
    int2*   cand = (int2*)(ws + OFF_CAND);

    // SCH must give an EVEN tile count (unroll x2): 5 -> CT=50; fallback 1 -> 250
    int SCH = 5;
    if ((size_t)OFF_CAND + (size_t)SCH * NPIX * sizeof(int2) > ws_size) SCH = 1;
    int CT = TILES_TOTAL / SCH;

    prep<<<(DATOMS + 255) / 256, 256, 0, stream>>>(db_mag, delta, A1, recf);
    dim3 grid(PXB, SCH);
    match<<<grid, 256, 0, stream>>>(A1, sig, delta, cand, CT);
    merge<<<(NPIX + 255) / 256, 256, 0, stream>>>(sig, recf, t2s, b1s, delta, cand,
                                                  (float*)d_out, SCH);
}